// Round 29
// baseline (394.523 us; speedup 1.0000x reference)
//
#include <hip/hip_runtime.h>
#include <hip/hip_bf16.h>

using u16 = unsigned short;
typedef short bf16x8 __attribute__((ext_vector_type(8)));
typedef float f32x4 __attribute__((ext_vector_type(4)));

#define MFMA16(a, b, c) __builtin_amdgcn_mfma_f32_16x16x32_bf16((a), (b), (c), 0, 0, 0)

__device__ __forceinline__ float bf2f(u16 u) {
  union { unsigned int i; float f; } v; v.i = ((unsigned int)u) << 16; return v.f;
}
__device__ __forceinline__ u16 f2bf(float f) {
  __hip_bfloat16 h = __float2bfloat16(f);
  return *reinterpret_cast<u16*>(&h);
}
__device__ __forceinline__ void gld_lds16(const void* g, void* l) {
  __builtin_amdgcn_global_load_lds(
      (const __attribute__((address_space(1))) void*)g,
      (__attribute__((address_space(3))) void*)l, 16, 0, 0);
}

// ---------------- fp32 -> bf16 convert (vec4) --------------------------
__global__ __launch_bounds__(256) void cvt_f32_bf16(
    const float* __restrict__ in, u16* __restrict__ out, int n8) {
  int i = blockIdx.x * 256 + threadIdx.x;
  if (i >= n8) return;
  f32x4 a = *(const f32x4*)&in[(size_t)i * 8];
  f32x4 b = *(const f32x4*)&in[(size_t)i * 8 + 4];
  bf16x8 o;
#pragma unroll
  for (int j = 0; j < 4; ++j) { o[j] = (short)f2bf(a[j]); o[4 + j] = (short)f2bf(b[j]); }
  *(bf16x8*)&out[(size_t)i * 8] = o;
}

// ---------------- transpose + convert: out[c][r] = bf16(in[r][c]) ------
__global__ __launch_bounds__(256) void transpose_cvt(
    const float* __restrict__ in, u16* __restrict__ out, int R, int C) {
  __shared__ float tile[32][33];
  int r0 = blockIdx.y * 32, c0 = blockIdx.x * 32;
  int tx = threadIdx.x, ty = threadIdx.y;
#pragma unroll
  for (int i = ty; i < 32; i += 8)
    tile[i][tx] = in[(size_t)(r0 + i) * C + c0 + tx];
  __syncthreads();
#pragma unroll
  for (int i = ty; i < 32; i += 8)
    out[(size_t)(c0 + i) * R + r0 + tx] = f2bf(tile[tx][i]);
}

// ---------------- QKV GEMM: A(8192x1024) * qkv_wT(3072x1024)^T + b ----
// K output is pre-scaled by 0.125 (= hd^-0.5) so attention's softmax
// needs no per-element scale multiplies.
#define TBM 128
#define TBN 128
#define TBK 64
#define SLD 136  // staging stride (u16): 272B rows -> 16B aligned
#define KSC 0.125f

__global__ __launch_bounds__(256) void qkv_gemm(
    const u16* __restrict__ A, const u16* __restrict__ Bt,
    const float* __restrict__ bias,
    u16* __restrict__ Qo, u16* __restrict__ Ko, u16* __restrict__ Vto) {
  const int K = 1024;
  __shared__ __align__(16) u16 LDSbuf[TBM * SLD];
  u16* Als = LDSbuf;
  u16* Bls = LDSbuf + TBM * TBK;
  int m0 = blockIdx.y * TBM, n0 = blockIdx.x * TBN;
  int tid = threadIdx.x;
  int w = tid >> 6, l = tid & 63, lr = l & 15, lg = l >> 4;
  int wm = w >> 1, wn = w & 1;

  f32x4 acc[4][4] = {};
  for (int k0 = 0; k0 < K; k0 += TBK) {
#pragma unroll
    for (int j = 0; j < 4; ++j) {
      int c = w * 4 + j;
      int e = c * 64 + l;
      int row = e >> 3, kq = (e & 7) * 8;
      gld_lds16(A + (size_t)(m0 + row) * K + k0 + kq, (char*)Als + (size_t)c * 1024);
      gld_lds16(Bt + (size_t)(n0 + row) * K + k0 + kq, (char*)Bls + (size_t)c * 1024);
    }
    __syncthreads();
#pragma unroll
    for (int ks = 0; ks < 2; ++ks) {
      bf16x8 a[4], b[4];
#pragma unroll
      for (int mt = 0; mt < 4; ++mt)
        a[mt] = *(const bf16x8*)&Als[(wm * 64 + mt * 16 + lr) * TBK + ks * 32 + lg * 8];
#pragma unroll
      for (int nt = 0; nt < 4; ++nt)
        b[nt] = *(const bf16x8*)&Bls[(wn * 64 + nt * 16 + lr) * TBK + ks * 32 + lg * 8];
#pragma unroll
      for (int mt = 0; mt < 4; ++mt)
#pragma unroll
        for (int nt = 0; nt < 4; ++nt)
          acc[mt][nt] = MFMA16(a[mt], b[nt], acc[mt][nt]);
    }
    __syncthreads();
  }

  int s = n0 >> 10;  // 0=Q, 1=K, 2=V
#pragma unroll
  for (int mt = 0; mt < 4; ++mt)
#pragma unroll
    for (int nt = 0; nt < 4; ++nt) {
      int nl = wn * 64 + nt * 16 + lr;
      float bv = bias[n0 + nl];
#pragma unroll
      for (int r = 0; r < 4; ++r) {
        int ml = wm * 64 + mt * 16 + lg * 4 + r;
        float av = acc[mt][nt][r] + bv;
        if (s == 1) av *= KSC;           // fold softmax scale into K
        u16 val = f2bf(av);
        if (s == 2) LDSbuf[nl * SLD + ml] = val;
        else        LDSbuf[ml * SLD + nl] = val;
      }
    }
  __syncthreads();

  int b_ = m0 >> 10;
  int tbase = m0 & 1023;
#pragma unroll
  for (int c = 0; c < 8; ++c) {
    int idx = c * 256 + tid;
    int row = idx >> 4, colE = (idx & 15) * 8;
    bf16x8 v = *(const bf16x8*)&LDSbuf[row * SLD + colE];
    if (s == 2) {
      int rr = (n0 + row) & 1023;
      int h = rr >> 6, d = rr & 63;
      int bh = b_ * 16 + h;
      *(bf16x8*)&Vto[((size_t)bh * 64 + d) * 1024 + tbase + colE] = v;
    } else {
      int t = tbase + row;
      int rr = (n0 + colE) & 1023;
      int h = rr >> 6, d = rr & 63;
      int bh = b_ * 16 + h;
      u16* dst = (s == 0) ? Qo : Ko;
      *(bf16x8*)&dst[((size_t)bh * 1024 + t) * 64 + d] = v;
    }
  }
}

// ---------------- out GEMM: O(8192x1024)bf16 * out_wT^T + b -> f32 ----
__global__ __launch_bounds__(256) void out_gemm(
    const u16* __restrict__ A, const u16* __restrict__ Bt,
    const float* __restrict__ bias, float* __restrict__ C) {
  const int K = 1024;
  __shared__ __align__(16) u16 Als[TBM * TBK];
  __shared__ __align__(16) u16 Bls[TBN * TBK];
  int m0 = blockIdx.y * TBM, n0 = blockIdx.x * TBN;
  int tid = threadIdx.x;
  int w = tid >> 6, l = tid & 63, lr = l & 15, lg = l >> 4;
  int wm = w >> 1, wn = w & 1;

  f32x4 acc[4][4] = {};
  for (int k0 = 0; k0 < K; k0 += TBK) {
#pragma unroll
    for (int j = 0; j < 4; ++j) {
      int c = w * 4 + j;
      int e = c * 64 + l;
      int row = e >> 3, kq = (e & 7) * 8;
      gld_lds16(A + (size_t)(m0 + row) * K + k0 + kq, (char*)Als + (size_t)c * 1024);
      gld_lds16(Bt + (size_t)(n0 + row) * K + k0 + kq, (char*)Bls + (size_t)c * 1024);
    }
    __syncthreads();
#pragma unroll
    for (int ks = 0; ks < 2; ++ks) {
      bf16x8 a[4], b[4];
#pragma unroll
      for (int mt = 0; mt < 4; ++mt)
        a[mt] = *(const bf16x8*)&Als[(wm * 64 + mt * 16 + lr) * TBK + ks * 32 + lg * 8];
#pragma unroll
      for (int nt = 0; nt < 4; ++nt)
        b[nt] = *(const bf16x8*)&Bls[(wn * 64 + nt * 16 + lr) * TBK + ks * 32 + lg * 8];
#pragma unroll
      for (int mt = 0; mt < 4; ++mt)
#pragma unroll
        for (int nt = 0; nt < 4; ++nt)
          acc[mt][nt] = MFMA16(a[mt], b[nt], acc[mt][nt]);
    }
    __syncthreads();
  }
#pragma unroll
  for (int mt = 0; mt < 4; ++mt)
#pragma unroll
    for (int nt = 0; nt < 4; ++nt) {
      int n = n0 + wn * 64 + nt * 16 + lr;
      float bv = bias[n];
#pragma unroll
      for (int r = 0; r < 4; ++r) {
        int m = m0 + wm * 64 + mt * 16 + lg * 4 + r;
        C[(size_t)m * 1024 + n] = acc[mt][nt][r] + bv;
      }
    }
}

// ---------------- attention, defer-normalized + XCD-chunked grid ------
// R27 structure with PLAIN (cache-combined) P stores instead of
// nontemporal — A/B test of nt-induced write amplification (R26 profile
// showed WRITE_SIZE 2.7x the logical 553 MB).
#define QB 32
#define PLD 1032  // 1024 + 8-elem (16B) pad

__global__ __launch_bounds__(512, 4) void attn_kernel(
    const u16* __restrict__ Q, const u16* __restrict__ K,
    const u16* __restrict__ Vt, float* __restrict__ Pout,
    u16* __restrict__ O) {
  __shared__ __align__(16) u16 Pls[QB * PLD];
  __shared__ __align__(16) u16 Qls[QB * 64];
  __shared__ float redM[8][QB];
  __shared__ float redS[8][QB];

  // XCD-chunked bijective remap (4096 = 8 XCD x 512)
  int bid = blockIdx.x;
  int wg = (bid & 7) * 512 + (bid >> 3);
  int bh = wg >> 5;
  int q0 = (wg & 31) * QB;
  int tid = threadIdx.x;
  int w = tid >> 6, l = tid & 63, lr = l & 15, lg = l >> 4;
  int wq = w >> 2, wd = w & 3;
  const u16* Qp = Q + ((size_t)bh * 1024 + q0) * 64;
  const u16* Kp = K + (size_t)bh * 1024 * 64;
  const u16* Vp = Vt + (size_t)bh * 64 * 1024;
  const u16* vrow = &Vp[(size_t)(wd * 16 + lr) * 1024 + lg * 8];

  if (tid < 256)
    *(bf16x8*)&Qls[tid * 8] = *(const bf16x8*)&Qp[tid * 8];

  // K-prefetch for QK^T ks=0 slice (8 fragments, 32 VGPR) — issued
  // before BAR0 so the first MFMAs after the barrier are load-free.
  bf16x8 kpre[8];
#pragma unroll
  for (int n = 0; n < 8; ++n)
    kpre[n] = *(const bf16x8*)&Kp[(size_t)(w * 128 + n * 16 + lr) * 64 + lg * 8];

  __syncthreads();  // BAR0: Qls ready

  // QK^T: wave w owns keys [w*128, w*128+128); S pre-scaled via K
  f32x4 sa[2][8] = {};
#pragma unroll
  for (int ks = 0; ks < 2; ++ks) {
    bf16x8 aq[2];
#pragma unroll
    for (int mt = 0; mt < 2; ++mt)
      aq[mt] = *(const bf16x8*)&Qls[(mt * 16 + lr) * 64 + ks * 32 + lg * 8];
#pragma unroll
    for (int n = 0; n < 8; ++n) {
      bf16x8 bk = (ks == 0) ? kpre[n]
          : *(const bf16x8*)&Kp[(size_t)(w * 128 + n * 16 + lr) * 64 + ks * 32 + lg * 8];
#pragma unroll
      for (int mt = 0; mt < 2; ++mt)
        sa[mt][n] = MFMA16(aq[mt], bk, sa[mt][n]);
    }
  }

  // wave-local softmax: sa -> exp(S - m_w), track (m_w, s_w)
#pragma unroll
  for (int mt = 0; mt < 2; ++mt)
#pragma unroll
    for (int r = 0; r < 4; ++r) {
      float m = -1e30f;
#pragma unroll
      for (int n = 0; n < 8; ++n)
        m = fmaxf(m, sa[mt][n][r]);
#pragma unroll
      for (int off = 1; off < 16; off <<= 1) m = fmaxf(m, __shfl_xor(m, off));
      float s = 0.f;
#pragma unroll
      for (int n = 0; n < 8; ++n) {
        float p = __expf(sa[mt][n][r] - m);
        sa[mt][n][r] = p;
        s += p;
      }
#pragma unroll
      for (int off = 1; off < 16; off <<= 1) s += __shfl_xor(s, off);
      int row = mt * 16 + lg * 4 + r;
      if (lr == 0) { redM[w][row] = m; redS[w][row] = s; }
      // unnormalized P (<=1) to LDS
#pragma unroll
      for (int n = 0; n < 8; ++n)
        Pls[row * PLD + w * 128 + n * 16 + lr] = f2bf(sa[mt][n][r]);
    }

  // V-prefetch for PV slices w2=0,1 (kt=0..7); sa is dead here, so the
  // 32 VGPRs fit under the launch_bounds 128 cap.
  bf16x8 vpre[8];
#pragma unroll
  for (int kt = 0; kt < 8; ++kt)
    vpre[kt] = *(const bf16x8*)&vrow[kt * 32];

  __syncthreads();  // BAR1: Pls + redM/S ready — last barrier

  // PV with read-side normalization: wave (wq,wd) -> 16q x 16d
  float Mr[4], invSr[4];
#pragma unroll
  for (int r = 0; r < 4; ++r) {
    int q = wq * 16 + lg * 4 + r;
    float M = -1e30f;
#pragma unroll
    for (int w2 = 0; w2 < 8; ++w2) M = fmaxf(M, redM[w2][q]);
    float S = 0.f;
#pragma unroll
    for (int w2 = 0; w2 < 8; ++w2) S += redS[w2][q] * __expf(redM[w2][q] - M);
    Mr[r] = M;
    invSr[r] = 1.f / S;
  }
  f32x4 oc = {};
#pragma unroll
  for (int w2 = 0; w2 < 8; ++w2) {
    f32x4 os = {};
#pragma unroll
    for (int kt2 = 0; kt2 < 4; ++kt2) {
      int kt = w2 * 4 + kt2;
      bf16x8 ap = *(const bf16x8*)&Pls[(wq * 16 + lr) * PLD + kt * 32 + lg * 8];
      bf16x8 bv = (w2 < 2) ? vpre[w2 * 4 + kt2] : *(const bf16x8*)&vrow[kt * 32];
      os = MFMA16(ap, bv, os);
    }
#pragma unroll
    for (int r = 0; r < 4; ++r) {
      int q = wq * 16 + lg * 4 + r;
      oc[r] += os[r] * (__expf(redM[w2][q] - Mr[r]) * invSr[r]);
    }
  }
  int b_ = bh >> 4, h = bh & 15;
#pragma unroll
  for (int r = 0; r < 4; ++r) {
    int q = q0 + wq * 16 + lg * 4 + r;
    O[((size_t)b_ * 1024 + q) * 1024 + h * 64 + wd * 16 + lr] = f2bf(oc[r]);
  }

  // P fp32 write, normalized read-side, PLAIN stores (L2 write-combine).
  // Thread -> fixed row (tid>>4), 16 threads/row; c8 = (tid&15)+it*16.
  {
    int row = tid >> 4;     // 0..31
    int cb = tid & 15;      // chunk base within 16
    float M = -1e30f;
#pragma unroll
    for (int w2 = 0; w2 < 8; ++w2) M = fmaxf(M, redM[w2][row]);
    float S = 0.f;
#pragma unroll
    for (int w2 = 0; w2 < 8; ++w2) S += redS[w2][row] * __expf(redM[w2][row] - M);
    float invS = 1.f / S;
    size_t pb = ((size_t)bh * 1024 + q0 + row) * 1024;
#pragma unroll
    for (int it = 0; it < 8; ++it) {
      float f = __expf(redM[it][row] - M) * invS;
      int c8 = it * 16 + cb;
      bf16x8 v = *(const bf16x8*)&Pls[row * PLD + c8 * 8];
      f32x4 a, b;
#pragma unroll
      for (int j = 0; j < 4; ++j) {
        a[j] = bf2f((u16)v[j]) * f;
        b[j] = bf2f((u16)v[4 + j]) * f;
      }
      size_t off = pb + (size_t)c8 * 8;
      *(f32x4*)&Pout[off] = a;
      *(f32x4*)&Pout[off + 4] = b;
    }
  }
}

extern "C" void kernel_launch(void* const* d_in, const int* in_sizes, int n_in,
                              void* d_out, int out_size, void* d_ws, size_t ws_size,
                              hipStream_t stream) {
  const float* seq   = (const float*)d_in[0];
  const float* qkv_w = (const float*)d_in[2];
  const float* qkv_b = (const float*)d_in[3];
  const float* out_w = (const float*)d_in[4];
  const float* out_b = (const float*)d_in[5];
  float* out = (float*)d_out;

  u16* seqb = (u16*)d_ws;
  u16* Qb   = seqb + 8388608;
  u16* Kb   = Qb + 8388608;
  u16* Vtb  = Kb + 8388608;
  u16* Ob   = Vtb + 8388608;
  u16* qkvT = Ob + 8388608;
  u16* owT  = qkvT + 3145728;

  cvt_f32_bf16<<<8388608 / (256 * 8), 256, 0, stream>>>(seq, seqb, 8388608 / 8);
  transpose_cvt<<<dim3(3072 / 32, 1024 / 32), dim3(32, 8), 0, stream>>>(qkv_w, qkvT, 1024, 3072);
  transpose_cvt<<<dim3(1024 / 32, 1024 / 32), dim3(32, 8), 0, stream>>>(out_w, owT, 1024, 1024);
  qkv_gemm<<<dim3(3072 / TBN, 8192 / TBM), 256, 0, stream>>>(seqb, qkvT, qkv_b, Qb, Kb, Vtb);
  attn_kernel<<<dim3(4096), 512, 0, stream>>>(Qb, Kb, Vtb, out + 8388608, Ob);
  out_gemm<<<dim3(1024 / TBN, 8192 / TBM), 256, 0, stream>>>(Ob, owT, out_b, out);
}

// Round 30
// 360.617 us; speedup vs baseline: 1.0940x; 1.0940x over previous
//
#include <hip/hip_runtime.h>
#include <hip/hip_bf16.h>

using u16 = unsigned short;
typedef short bf16x8 __attribute__((ext_vector_type(8)));
typedef float f32x4 __attribute__((ext_vector_type(4)));

#define MFMA16(a, b, c) __builtin_amdgcn_mfma_f32_16x16x32_bf16((a), (b), (c), 0, 0, 0)

__device__ __forceinline__ float bf2f(u16 u) {
  union { unsigned int i; float f; } v; v.i = ((unsigned int)u) << 16; return v.f;
}
__device__ __forceinline__ u16 f2bf(float f) {
  __hip_bfloat16 h = __float2bfloat16(f);
  return *reinterpret_cast<u16*>(&h);
}
__device__ __forceinline__ void gld_lds16(const void* g, void* l) {
  __builtin_amdgcn_global_load_lds(
      (const __attribute__((address_space(1))) void*)g,
      (__attribute__((address_space(3))) void*)l, 16, 0, 0);
}

// ---------------- fp32 -> bf16 convert (vec4) --------------------------
__global__ __launch_bounds__(256) void cvt_f32_bf16(
    const float* __restrict__ in, u16* __restrict__ out, int n8) {
  int i = blockIdx.x * 256 + threadIdx.x;
  if (i >= n8) return;
  f32x4 a = *(const f32x4*)&in[(size_t)i * 8];
  f32x4 b = *(const f32x4*)&in[(size_t)i * 8 + 4];
  bf16x8 o;
#pragma unroll
  for (int j = 0; j < 4; ++j) { o[j] = (short)f2bf(a[j]); o[4 + j] = (short)f2bf(b[j]); }
  *(bf16x8*)&out[(size_t)i * 8] = o;
}

// ---------------- transpose + convert: out[c][r] = bf16(in[r][c]) ------
__global__ __launch_bounds__(256) void transpose_cvt(
    const float* __restrict__ in, u16* __restrict__ out, int R, int C) {
  __shared__ float tile[32][33];
  int r0 = blockIdx.y * 32, c0 = blockIdx.x * 32;
  int tx = threadIdx.x, ty = threadIdx.y;
#pragma unroll
  for (int i = ty; i < 32; i += 8)
    tile[i][tx] = in[(size_t)(r0 + i) * C + c0 + tx];
  __syncthreads();
#pragma unroll
  for (int i = ty; i < 32; i += 8)
    out[(size_t)(c0 + i) * R + r0 + tx] = f2bf(tile[tx][i]);
}

// ---------------- QKV GEMM: A(8192x1024) * qkv_wT(3072x1024)^T + b ----
// K output is pre-scaled by 0.125 (= hd^-0.5) so attention's softmax
// needs no per-element scale multiplies.
#define TBM 128
#define TBN 128
#define TBK 64
#define SLD 136  // staging stride (u16): 272B rows -> 16B aligned
#define KSC 0.125f

__global__ __launch_bounds__(256) void qkv_gemm(
    const u16* __restrict__ A, const u16* __restrict__ Bt,
    const float* __restrict__ bias,
    u16* __restrict__ Qo, u16* __restrict__ Ko, u16* __restrict__ Vto) {
  const int K = 1024;
  __shared__ __align__(16) u16 LDSbuf[TBM * SLD];
  u16* Als = LDSbuf;
  u16* Bls = LDSbuf + TBM * TBK;
  int m0 = blockIdx.y * TBM, n0 = blockIdx.x * TBN;
  int tid = threadIdx.x;
  int w = tid >> 6, l = tid & 63, lr = l & 15, lg = l >> 4;
  int wm = w >> 1, wn = w & 1;

  f32x4 acc[4][4] = {};
  for (int k0 = 0; k0 < K; k0 += TBK) {
#pragma unroll
    for (int j = 0; j < 4; ++j) {
      int c = w * 4 + j;
      int e = c * 64 + l;
      int row = e >> 3, kq = (e & 7) * 8;
      gld_lds16(A + (size_t)(m0 + row) * K + k0 + kq, (char*)Als + (size_t)c * 1024);
      gld_lds16(Bt + (size_t)(n0 + row) * K + k0 + kq, (char*)Bls + (size_t)c * 1024);
    }
    __syncthreads();
#pragma unroll
    for (int ks = 0; ks < 2; ++ks) {
      bf16x8 a[4], b[4];
#pragma unroll
      for (int mt = 0; mt < 4; ++mt)
        a[mt] = *(const bf16x8*)&Als[(wm * 64 + mt * 16 + lr) * TBK + ks * 32 + lg * 8];
#pragma unroll
      for (int nt = 0; nt < 4; ++nt)
        b[nt] = *(const bf16x8*)&Bls[(wn * 64 + nt * 16 + lr) * TBK + ks * 32 + lg * 8];
#pragma unroll
      for (int mt = 0; mt < 4; ++mt)
#pragma unroll
        for (int nt = 0; nt < 4; ++nt)
          acc[mt][nt] = MFMA16(a[mt], b[nt], acc[mt][nt]);
    }
    __syncthreads();
  }

  int s = n0 >> 10;  // 0=Q, 1=K, 2=V
#pragma unroll
  for (int mt = 0; mt < 4; ++mt)
#pragma unroll
    for (int nt = 0; nt < 4; ++nt) {
      int nl = wn * 64 + nt * 16 + lr;
      float bv = bias[n0 + nl];
#pragma unroll
      for (int r = 0; r < 4; ++r) {
        int ml = wm * 64 + mt * 16 + lg * 4 + r;
        float av = acc[mt][nt][r] + bv;
        if (s == 1) av *= KSC;           // fold softmax scale into K
        u16 val = f2bf(av);
        if (s == 2) LDSbuf[nl * SLD + ml] = val;
        else        LDSbuf[ml * SLD + nl] = val;
      }
    }
  __syncthreads();

  int b_ = m0 >> 10;
  int tbase = m0 & 1023;
#pragma unroll
  for (int c = 0; c < 8; ++c) {
    int idx = c * 256 + tid;
    int row = idx >> 4, colE = (idx & 15) * 8;
    bf16x8 v = *(const bf16x8*)&LDSbuf[row * SLD + colE];
    if (s == 2) {
      int rr = (n0 + row) & 1023;
      int h = rr >> 6, d = rr & 63;
      int bh = b_ * 16 + h;
      *(bf16x8*)&Vto[((size_t)bh * 64 + d) * 1024 + tbase + colE] = v;
    } else {
      int t = tbase + row;
      int rr = (n0 + colE) & 1023;
      int h = rr >> 6, d = rr & 63;
      int bh = b_ * 16 + h;
      u16* dst = (s == 0) ? Qo : Ko;
      *(bf16x8*)&dst[((size_t)bh * 1024 + t) * 64 + d] = v;
    }
  }
}

// ---------------- out GEMM: O(8192x1024)bf16 * out_wT^T + b -> f32 ----
__global__ __launch_bounds__(256) void out_gemm(
    const u16* __restrict__ A, const u16* __restrict__ Bt,
    const float* __restrict__ bias, float* __restrict__ C) {
  const int K = 1024;
  __shared__ __align__(16) u16 Als[TBM * TBK];
  __shared__ __align__(16) u16 Bls[TBN * TBK];
  int m0 = blockIdx.y * TBM, n0 = blockIdx.x * TBN;
  int tid = threadIdx.x;
  int w = tid >> 6, l = tid & 63, lr = l & 15, lg = l >> 4;
  int wm = w >> 1, wn = w & 1;

  f32x4 acc[4][4] = {};
  for (int k0 = 0; k0 < K; k0 += TBK) {
#pragma unroll
    for (int j = 0; j < 4; ++j) {
      int c = w * 4 + j;
      int e = c * 64 + l;
      int row = e >> 3, kq = (e & 7) * 8;
      gld_lds16(A + (size_t)(m0 + row) * K + k0 + kq, (char*)Als + (size_t)c * 1024);
      gld_lds16(Bt + (size_t)(n0 + row) * K + k0 + kq, (char*)Bls + (size_t)c * 1024);
    }
    __syncthreads();
#pragma unroll
    for (int ks = 0; ks < 2; ++ks) {
      bf16x8 a[4], b[4];
#pragma unroll
      for (int mt = 0; mt < 4; ++mt)
        a[mt] = *(const bf16x8*)&Als[(wm * 64 + mt * 16 + lr) * TBK + ks * 32 + lg * 8];
#pragma unroll
      for (int nt = 0; nt < 4; ++nt)
        b[nt] = *(const bf16x8*)&Bls[(wn * 64 + nt * 16 + lr) * TBK + ks * 32 + lg * 8];
#pragma unroll
      for (int mt = 0; mt < 4; ++mt)
#pragma unroll
        for (int nt = 0; nt < 4; ++nt)
          acc[mt][nt] = MFMA16(a[mt], b[nt], acc[mt][nt]);
    }
    __syncthreads();
  }
#pragma unroll
  for (int mt = 0; mt < 4; ++mt)
#pragma unroll
    for (int nt = 0; nt < 4; ++nt) {
      int n = n0 + wn * 64 + nt * 16 + lr;
      float bv = bias[n];
#pragma unroll
      for (int r = 0; r < 4; ++r) {
        int m = m0 + wm * 64 + mt * 16 + lg * 4 + r;
        C[(size_t)m * 1024 + n] = acc[mt][nt][r] + bv;
      }
    }
}

// ---------------- attention, defer-normalized + XCD-chunked grid ------
// FINAL config (360.6-361.5us, 5 runs): 2-barrier defer-normalized
// softmax, K-prefetch across BAR0, V-prefetch depth 8 across BAR1,
// NONTEMPORAL P stores (A/B-confirmed -33us vs plain: write-once P must
// not thrash L2), softmax scale folded into K.
#define QB 32
#define PLD 1032  // 1024 + 8-elem (16B) pad

__global__ __launch_bounds__(512, 4) void attn_kernel(
    const u16* __restrict__ Q, const u16* __restrict__ K,
    const u16* __restrict__ Vt, float* __restrict__ Pout,
    u16* __restrict__ O) {
  __shared__ __align__(16) u16 Pls[QB * PLD];
  __shared__ __align__(16) u16 Qls[QB * 64];
  __shared__ float redM[8][QB];
  __shared__ float redS[8][QB];

  // XCD-chunked bijective remap (4096 = 8 XCD x 512)
  int bid = blockIdx.x;
  int wg = (bid & 7) * 512 + (bid >> 3);
  int bh = wg >> 5;
  int q0 = (wg & 31) * QB;
  int tid = threadIdx.x;
  int w = tid >> 6, l = tid & 63, lr = l & 15, lg = l >> 4;
  int wq = w >> 2, wd = w & 3;
  const u16* Qp = Q + ((size_t)bh * 1024 + q0) * 64;
  const u16* Kp = K + (size_t)bh * 1024 * 64;
  const u16* Vp = Vt + (size_t)bh * 64 * 1024;
  const u16* vrow = &Vp[(size_t)(wd * 16 + lr) * 1024 + lg * 8];

  if (tid < 256)
    *(bf16x8*)&Qls[tid * 8] = *(const bf16x8*)&Qp[tid * 8];

  // K-prefetch for QK^T ks=0 slice (8 fragments, 32 VGPR) — issued
  // before BAR0 so the first MFMAs after the barrier are load-free.
  bf16x8 kpre[8];
#pragma unroll
  for (int n = 0; n < 8; ++n)
    kpre[n] = *(const bf16x8*)&Kp[(size_t)(w * 128 + n * 16 + lr) * 64 + lg * 8];

  __syncthreads();  // BAR0: Qls ready

  // QK^T: wave w owns keys [w*128, w*128+128); S pre-scaled via K
  f32x4 sa[2][8] = {};
#pragma unroll
  for (int ks = 0; ks < 2; ++ks) {
    bf16x8 aq[2];
#pragma unroll
    for (int mt = 0; mt < 2; ++mt)
      aq[mt] = *(const bf16x8*)&Qls[(mt * 16 + lr) * 64 + ks * 32 + lg * 8];
#pragma unroll
    for (int n = 0; n < 8; ++n) {
      bf16x8 bk = (ks == 0) ? kpre[n]
          : *(const bf16x8*)&Kp[(size_t)(w * 128 + n * 16 + lr) * 64 + ks * 32 + lg * 8];
#pragma unroll
      for (int mt = 0; mt < 2; ++mt)
        sa[mt][n] = MFMA16(aq[mt], bk, sa[mt][n]);
    }
  }

  // wave-local softmax: sa -> exp(S - m_w), track (m_w, s_w)
#pragma unroll
  for (int mt = 0; mt < 2; ++mt)
#pragma unroll
    for (int r = 0; r < 4; ++r) {
      float m = -1e30f;
#pragma unroll
      for (int n = 0; n < 8; ++n)
        m = fmaxf(m, sa[mt][n][r]);
#pragma unroll
      for (int off = 1; off < 16; off <<= 1) m = fmaxf(m, __shfl_xor(m, off));
      float s = 0.f;
#pragma unroll
      for (int n = 0; n < 8; ++n) {
        float p = __expf(sa[mt][n][r] - m);
        sa[mt][n][r] = p;
        s += p;
      }
#pragma unroll
      for (int off = 1; off < 16; off <<= 1) s += __shfl_xor(s, off);
      int row = mt * 16 + lg * 4 + r;
      if (lr == 0) { redM[w][row] = m; redS[w][row] = s; }
      // unnormalized P (<=1) to LDS
#pragma unroll
      for (int n = 0; n < 8; ++n)
        Pls[row * PLD + w * 128 + n * 16 + lr] = f2bf(sa[mt][n][r]);
    }

  // V-prefetch for PV slices w2=0,1 (kt=0..7); sa is dead here, so the
  // 32 VGPRs fit under the launch_bounds 128 cap.
  bf16x8 vpre[8];
#pragma unroll
  for (int kt = 0; kt < 8; ++kt)
    vpre[kt] = *(const bf16x8*)&vrow[kt * 32];

  __syncthreads();  // BAR1: Pls + redM/S ready — last barrier

  // PV with read-side normalization: wave (wq,wd) -> 16q x 16d
  float Mr[4], invSr[4];
#pragma unroll
  for (int r = 0; r < 4; ++r) {
    int q = wq * 16 + lg * 4 + r;
    float M = -1e30f;
#pragma unroll
    for (int w2 = 0; w2 < 8; ++w2) M = fmaxf(M, redM[w2][q]);
    float S = 0.f;
#pragma unroll
    for (int w2 = 0; w2 < 8; ++w2) S += redS[w2][q] * __expf(redM[w2][q] - M);
    Mr[r] = M;
    invSr[r] = 1.f / S;
  }
  f32x4 oc = {};
#pragma unroll
  for (int w2 = 0; w2 < 8; ++w2) {
    f32x4 os = {};
#pragma unroll
    for (int kt2 = 0; kt2 < 4; ++kt2) {
      int kt = w2 * 4 + kt2;
      bf16x8 ap = *(const bf16x8*)&Pls[(wq * 16 + lr) * PLD + kt * 32 + lg * 8];
      bf16x8 bv = (w2 < 2) ? vpre[w2 * 4 + kt2] : *(const bf16x8*)&vrow[kt * 32];
      os = MFMA16(ap, bv, os);
    }
#pragma unroll
    for (int r = 0; r < 4; ++r) {
      int q = wq * 16 + lg * 4 + r;
      oc[r] += os[r] * (__expf(redM[w2][q] - Mr[r]) * invSr[r]);
    }
  }
  int b_ = bh >> 4, h = bh & 15;
#pragma unroll
  for (int r = 0; r < 4; ++r) {
    int q = q0 + wq * 16 + lg * 4 + r;
    O[((size_t)b_ * 1024 + q) * 1024 + h * 64 + wd * 16 + lr] = f2bf(oc[r]);
  }

  // P fp32 write, normalized read-side, nontemporal. Thread -> fixed
  // row (tid>>4), 16 threads/row; chunk c8 = (tid&15)+it*16 so w2 == it.
  {
    int row = tid >> 4;     // 0..31
    int cb = tid & 15;      // chunk base within 16
    float M = -1e30f;
#pragma unroll
    for (int w2 = 0; w2 < 8; ++w2) M = fmaxf(M, redM[w2][row]);
    float S = 0.f;
#pragma unroll
    for (int w2 = 0; w2 < 8; ++w2) S += redS[w2][row] * __expf(redM[w2][row] - M);
    float invS = 1.f / S;
    size_t pb = ((size_t)bh * 1024 + q0 + row) * 1024;
#pragma unroll
    for (int it = 0; it < 8; ++it) {
      float f = __expf(redM[it][row] - M) * invS;
      int c8 = it * 16 + cb;
      bf16x8 v = *(const bf16x8*)&Pls[row * PLD + c8 * 8];
      f32x4 a, b;
#pragma unroll
      for (int j = 0; j < 4; ++j) {
        a[j] = bf2f((u16)v[j]) * f;
        b[j] = bf2f((u16)v[4 + j]) * f;
      }
      size_t off = pb + (size_t)c8 * 8;
      __builtin_nontemporal_store(a, (f32x4*)&Pout[off]);
      __builtin_nontemporal_store(b, (f32x4*)&Pout[off + 4]);
    }
  }
}

extern "C" void kernel_launch(void* const* d_in, const int* in_sizes, int n_in,
                              void* d_out, int out_size, void* d_ws, size_t ws_size,
                              hipStream_t stream) {
  const float* seq   = (const float*)d_in[0];
  const float* qkv_w = (const float*)d_in[2];
  const float* qkv_b = (const float*)d_in[3];
  const float* out_w = (const float*)d_in[4];
  const float* out_b = (const float*)d_in[5];
  float* out = (float*)d_out;

  u16* seqb = (u16*)d_ws;
  u16* Qb   = seqb + 8388608;
  u16* Kb   = Qb + 8388608;
  u16* Vtb  = Kb + 8388608;
  u16* Ob   = Vtb + 8388608;
  u16* qkvT = Ob + 8388608;
  u16* owT  = qkvT + 3145728;

  cvt_f32_bf16<<<8388608 / (256 * 8), 256, 0, stream>>>(seq, seqb, 8388608 / 8);
  transpose_cvt<<<dim3(3072 / 32, 1024 / 32), dim3(32, 8), 0, stream>>>(qkv_w, qkvT, 1024, 3072);
  transpose_cvt<<<dim3(1024 / 32, 1024 / 32), dim3(32, 8), 0, stream>>>(out_w, owT, 1024, 1024);
  qkv_gemm<<<dim3(3072 / TBN, 8192 / TBM), 256, 0, stream>>>(seqb, qkvT, qkv_b, Qb, Kb, Vtb);
  attn_kernel<<<dim3(4096), 512, 0, stream>>>(Qb, Kb, Vtb, out + 8388608, Ob);
  out_gemm<<<dim3(1024 / TBN, 8192 / TBM), 256, 0, stream>>>(Ob, owT, out_b, out);
}

// Round 31
// 360.128 us; speedup vs baseline: 1.0955x; 1.0014x over previous
//
#include <hip/hip_runtime.h>
#include <hip/hip_bf16.h>

using u16 = unsigned short;
typedef short bf16x8 __attribute__((ext_vector_type(8)));
typedef float f32x4 __attribute__((ext_vector_type(4)));

#define MFMA16(a, b, c) __builtin_amdgcn_mfma_f32_16x16x32_bf16((a), (b), (c), 0, 0, 0)

__device__ __forceinline__ float bf2f(u16 u) {
  union { unsigned int i; float f; } v; v.i = ((unsigned int)u) << 16; return v.f;
}
__device__ __forceinline__ u16 f2bf(float f) {
  __hip_bfloat16 h = __float2bfloat16(f);
  return *reinterpret_cast<u16*>(&h);
}
__device__ __forceinline__ void gld_lds16(const void* g, void* l) {
  __builtin_amdgcn_global_load_lds(
      (const __attribute__((address_space(1))) void*)g,
      (__attribute__((address_space(3))) void*)l, 16, 0, 0);
}

// ---------------- fp32 -> bf16 convert (vec4) --------------------------
__global__ __launch_bounds__(256) void cvt_f32_bf16(
    const float* __restrict__ in, u16* __restrict__ out, int n8) {
  int i = blockIdx.x * 256 + threadIdx.x;
  if (i >= n8) return;
  f32x4 a = *(const f32x4*)&in[(size_t)i * 8];
  f32x4 b = *(const f32x4*)&in[(size_t)i * 8 + 4];
  bf16x8 o;
#pragma unroll
  for (int j = 0; j < 4; ++j) { o[j] = (short)f2bf(a[j]); o[4 + j] = (short)f2bf(b[j]); }
  *(bf16x8*)&out[(size_t)i * 8] = o;
}

// ---------------- transpose + convert: out[c][r] = bf16(in[r][c]) ------
__global__ __launch_bounds__(256) void transpose_cvt(
    const float* __restrict__ in, u16* __restrict__ out, int R, int C) {
  __shared__ float tile[32][33];
  int r0 = blockIdx.y * 32, c0 = blockIdx.x * 32;
  int tx = threadIdx.x, ty = threadIdx.y;
#pragma unroll
  for (int i = ty; i < 32; i += 8)
    tile[i][tx] = in[(size_t)(r0 + i) * C + c0 + tx];
  __syncthreads();
#pragma unroll
  for (int i = ty; i < 32; i += 8)
    out[(size_t)(c0 + i) * R + r0 + tx] = f2bf(tile[tx][i]);
}

// ---------------- QKV GEMM: A(8192x1024) * qkv_wT(3072x1024)^T + b ----
// K output is pre-scaled by 0.125 (= hd^-0.5) so attention's softmax
// needs no per-element scale multiplies.
#define TBM 128
#define TBN 128
#define TBK 64
#define SLD 136  // staging stride (u16): 272B rows -> 16B aligned
#define KSC 0.125f

__global__ __launch_bounds__(256) void qkv_gemm(
    const u16* __restrict__ A, const u16* __restrict__ Bt,
    const float* __restrict__ bias,
    u16* __restrict__ Qo, u16* __restrict__ Ko, u16* __restrict__ Vto) {
  const int K = 1024;
  __shared__ __align__(16) u16 LDSbuf[TBM * SLD];
  u16* Als = LDSbuf;
  u16* Bls = LDSbuf + TBM * TBK;
  int m0 = blockIdx.y * TBM, n0 = blockIdx.x * TBN;
  int tid = threadIdx.x;
  int w = tid >> 6, l = tid & 63, lr = l & 15, lg = l >> 4;
  int wm = w >> 1, wn = w & 1;

  f32x4 acc[4][4] = {};
  for (int k0 = 0; k0 < K; k0 += TBK) {
#pragma unroll
    for (int j = 0; j < 4; ++j) {
      int c = w * 4 + j;
      int e = c * 64 + l;
      int row = e >> 3, kq = (e & 7) * 8;
      gld_lds16(A + (size_t)(m0 + row) * K + k0 + kq, (char*)Als + (size_t)c * 1024);
      gld_lds16(Bt + (size_t)(n0 + row) * K + k0 + kq, (char*)Bls + (size_t)c * 1024);
    }
    __syncthreads();
#pragma unroll
    for (int ks = 0; ks < 2; ++ks) {
      bf16x8 a[4], b[4];
#pragma unroll
      for (int mt = 0; mt < 4; ++mt)
        a[mt] = *(const bf16x8*)&Als[(wm * 64 + mt * 16 + lr) * TBK + ks * 32 + lg * 8];
#pragma unroll
      for (int nt = 0; nt < 4; ++nt)
        b[nt] = *(const bf16x8*)&Bls[(wn * 64 + nt * 16 + lr) * TBK + ks * 32 + lg * 8];
#pragma unroll
      for (int mt = 0; mt < 4; ++mt)
#pragma unroll
        for (int nt = 0; nt < 4; ++nt)
          acc[mt][nt] = MFMA16(a[mt], b[nt], acc[mt][nt]);
    }
    __syncthreads();
  }

  int s = n0 >> 10;  // 0=Q, 1=K, 2=V
#pragma unroll
  for (int mt = 0; mt < 4; ++mt)
#pragma unroll
    for (int nt = 0; nt < 4; ++nt) {
      int nl = wn * 64 + nt * 16 + lr;
      float bv = bias[n0 + nl];
#pragma unroll
      for (int r = 0; r < 4; ++r) {
        int ml = wm * 64 + mt * 16 + lg * 4 + r;
        float av = acc[mt][nt][r] + bv;
        if (s == 1) av *= KSC;           // fold softmax scale into K
        u16 val = f2bf(av);
        if (s == 2) LDSbuf[nl * SLD + ml] = val;
        else        LDSbuf[ml * SLD + nl] = val;
      }
    }
  __syncthreads();

  int b_ = m0 >> 10;
  int tbase = m0 & 1023;
#pragma unroll
  for (int c = 0; c < 8; ++c) {
    int idx = c * 256 + tid;
    int row = idx >> 4, colE = (idx & 15) * 8;
    bf16x8 v = *(const bf16x8*)&LDSbuf[row * SLD + colE];
    if (s == 2) {
      int rr = (n0 + row) & 1023;
      int h = rr >> 6, d = rr & 63;
      int bh = b_ * 16 + h;
      *(bf16x8*)&Vto[((size_t)bh * 64 + d) * 1024 + tbase + colE] = v;
    } else {
      int t = tbase + row;
      int rr = (n0 + colE) & 1023;
      int h = rr >> 6, d = rr & 63;
      int bh = b_ * 16 + h;
      u16* dst = (s == 0) ? Qo : Ko;
      *(bf16x8*)&dst[((size_t)bh * 1024 + t) * 64 + d] = v;
    }
  }
}

// ---------------- out GEMM: O(8192x1024)bf16 * out_wT^T + b -> f32 ----
__global__ __launch_bounds__(256) void out_gemm(
    const u16* __restrict__ A, const u16* __restrict__ Bt,
    const float* __restrict__ bias, float* __restrict__ C) {
  const int K = 1024;
  __shared__ __align__(16) u16 Als[TBM * TBK];
  __shared__ __align__(16) u16 Bls[TBN * TBK];
  int m0 = blockIdx.y * TBM, n0 = blockIdx.x * TBN;
  int tid = threadIdx.x;
  int w = tid >> 6, l = tid & 63, lr = l & 15, lg = l >> 4;
  int wm = w >> 1, wn = w & 1;

  f32x4 acc[4][4] = {};
  for (int k0 = 0; k0 < K; k0 += TBK) {
#pragma unroll
    for (int j = 0; j < 4; ++j) {
      int c = w * 4 + j;
      int e = c * 64 + l;
      int row = e >> 3, kq = (e & 7) * 8;
      gld_lds16(A + (size_t)(m0 + row) * K + k0 + kq, (char*)Als + (size_t)c * 1024);
      gld_lds16(Bt + (size_t)(n0 + row) * K + k0 + kq, (char*)Bls + (size_t)c * 1024);
    }
    __syncthreads();
#pragma unroll
    for (int ks = 0; ks < 2; ++ks) {
      bf16x8 a[4], b[4];
#pragma unroll
      for (int mt = 0; mt < 4; ++mt)
        a[mt] = *(const bf16x8*)&Als[(wm * 64 + mt * 16 + lr) * TBK + ks * 32 + lg * 8];
#pragma unroll
      for (int nt = 0; nt < 4; ++nt)
        b[nt] = *(const bf16x8*)&Bls[(wn * 64 + nt * 16 + lr) * TBK + ks * 32 + lg * 8];
#pragma unroll
      for (int mt = 0; mt < 4; ++mt)
#pragma unroll
        for (int nt = 0; nt < 4; ++nt)
          acc[mt][nt] = MFMA16(a[mt], b[nt], acc[mt][nt]);
    }
    __syncthreads();
  }
#pragma unroll
  for (int mt = 0; mt < 4; ++mt)
#pragma unroll
    for (int nt = 0; nt < 4; ++nt) {
      int n = n0 + wn * 64 + nt * 16 + lr;
      float bv = bias[n];
#pragma unroll
      for (int r = 0; r < 4; ++r) {
        int m = m0 + wm * 64 + mt * 16 + lg * 4 + r;
        C[(size_t)m * 1024 + n] = acc[mt][nt][r] + bv;
      }
    }
}

// ---------------- attention, defer-normalized + XCD-chunked grid ------
// FINAL config (360.6-361.5us, 6 runs): 2-barrier defer-normalized
// softmax, K-prefetch across BAR0, V-prefetch depth 8 across BAR1,
// NONTEMPORAL P stores (A/B-confirmed -33us vs plain), scale in K.
#define QB 32
#define PLD 1032  // 1024 + 8-elem (16B) pad

__global__ __launch_bounds__(512, 4) void attn_kernel(
    const u16* __restrict__ Q, const u16* __restrict__ K,
    const u16* __restrict__ Vt, float* __restrict__ Pout,
    u16* __restrict__ O) {
  __shared__ __align__(16) u16 Pls[QB * PLD];
  __shared__ __align__(16) u16 Qls[QB * 64];
  __shared__ float redM[8][QB];
  __shared__ float redS[8][QB];

  // XCD-chunked bijective remap (4096 = 8 XCD x 512)
  int bid = blockIdx.x;
  int wg = (bid & 7) * 512 + (bid >> 3);
  int bh = wg >> 5;
  int q0 = (wg & 31) * QB;
  int tid = threadIdx.x;
  int w = tid >> 6, l = tid & 63, lr = l & 15, lg = l >> 4;
  int wq = w >> 2, wd = w & 3;
  const u16* Qp = Q + ((size_t)bh * 1024 + q0) * 64;
  const u16* Kp = K + (size_t)bh * 1024 * 64;
  const u16* Vp = Vt + (size_t)bh * 64 * 1024;
  const u16* vrow = &Vp[(size_t)(wd * 16 + lr) * 1024 + lg * 8];

  if (tid < 256)
    *(bf16x8*)&Qls[tid * 8] = *(const bf16x8*)&Qp[tid * 8];

  // K-prefetch for QK^T ks=0 slice (8 fragments, 32 VGPR) — issued
  // before BAR0 so the first MFMAs after the barrier are load-free.
  bf16x8 kpre[8];
#pragma unroll
  for (int n = 0; n < 8; ++n)
    kpre[n] = *(const bf16x8*)&Kp[(size_t)(w * 128 + n * 16 + lr) * 64 + lg * 8];

  __syncthreads();  // BAR0: Qls ready

  // QK^T: wave w owns keys [w*128, w*128+128); S pre-scaled via K
  f32x4 sa[2][8] = {};
#pragma unroll
  for (int ks = 0; ks < 2; ++ks) {
    bf16x8 aq[2];
#pragma unroll
    for (int mt = 0; mt < 2; ++mt)
      aq[mt] = *(const bf16x8*)&Qls[(mt * 16 + lr) * 64 + ks * 32 + lg * 8];
#pragma unroll
    for (int n = 0; n < 8; ++n) {
      bf16x8 bk = (ks == 0) ? kpre[n]
          : *(const bf16x8*)&Kp[(size_t)(w * 128 + n * 16 + lr) * 64 + ks * 32 + lg * 8];
#pragma unroll
      for (int mt = 0; mt < 2; ++mt)
        sa[mt][n] = MFMA16(aq[mt], bk, sa[mt][n]);
    }
  }

  // wave-local softmax: sa -> exp(S - m_w), track (m_w, s_w)
#pragma unroll
  for (int mt = 0; mt < 2; ++mt)
#pragma unroll
    for (int r = 0; r < 4; ++r) {
      float m = -1e30f;
#pragma unroll
      for (int n = 0; n < 8; ++n)
        m = fmaxf(m, sa[mt][n][r]);
#pragma unroll
      for (int off = 1; off < 16; off <<= 1) m = fmaxf(m, __shfl_xor(m, off));
      float s = 0.f;
#pragma unroll
      for (int n = 0; n < 8; ++n) {
        float p = __expf(sa[mt][n][r] - m);
        sa[mt][n][r] = p;
        s += p;
      }
#pragma unroll
      for (int off = 1; off < 16; off <<= 1) s += __shfl_xor(s, off);
      int row = mt * 16 + lg * 4 + r;
      if (lr == 0) { redM[w][row] = m; redS[w][row] = s; }
      // unnormalized P (<=1) to LDS
#pragma unroll
      for (int n = 0; n < 8; ++n)
        Pls[row * PLD + w * 128 + n * 16 + lr] = f2bf(sa[mt][n][r]);
    }

  // V-prefetch for PV slices w2=0,1 (kt=0..7); sa is dead here, so the
  // 32 VGPRs fit under the launch_bounds 128 cap.
  bf16x8 vpre[8];
#pragma unroll
  for (int kt = 0; kt < 8; ++kt)
    vpre[kt] = *(const bf16x8*)&vrow[kt * 32];

  __syncthreads();  // BAR1: Pls + redM/S ready — last barrier

  // PV with read-side normalization: wave (wq,wd) -> 16q x 16d
  float Mr[4], invSr[4];
#pragma unroll
  for (int r = 0; r < 4; ++r) {
    int q = wq * 16 + lg * 4 + r;
    float M = -1e30f;
#pragma unroll
    for (int w2 = 0; w2 < 8; ++w2) M = fmaxf(M, redM[w2][q]);
    float S = 0.f;
#pragma unroll
    for (int w2 = 0; w2 < 8; ++w2) S += redS[w2][q] * __expf(redM[w2][q] - M);
    Mr[r] = M;
    invSr[r] = 1.f / S;
  }
  f32x4 oc = {};
#pragma unroll
  for (int w2 = 0; w2 < 8; ++w2) {
    f32x4 os = {};
#pragma unroll
    for (int kt2 = 0; kt2 < 4; ++kt2) {
      int kt = w2 * 4 + kt2;
      bf16x8 ap = *(const bf16x8*)&Pls[(wq * 16 + lr) * PLD + kt * 32 + lg * 8];
      bf16x8 bv = (w2 < 2) ? vpre[w2 * 4 + kt2] : *(const bf16x8*)&vrow[kt * 32];
      os = MFMA16(ap, bv, os);
    }
#pragma unroll
    for (int r = 0; r < 4; ++r) {
      int q = wq * 16 + lg * 4 + r;
      oc[r] += os[r] * (__expf(redM[w2][q] - Mr[r]) * invSr[r]);
    }
  }
  int b_ = bh >> 4, h = bh & 15;
#pragma unroll
  for (int r = 0; r < 4; ++r) {
    int q = q0 + wq * 16 + lg * 4 + r;
    O[((size_t)b_ * 1024 + q) * 1024 + h * 64 + wd * 16 + lr] = f2bf(oc[r]);
  }

  // P fp32 write, normalized read-side, nontemporal. Thread -> fixed
  // row (tid>>4), 16 threads/row; chunk c8 = (tid&15)+it*16 so w2 == it.
  {
    int row = tid >> 4;     // 0..31
    int cb = tid & 15;      // chunk base within 16
    float M = -1e30f;
#pragma unroll
    for (int w2 = 0; w2 < 8; ++w2) M = fmaxf(M, redM[w2][row]);
    float S = 0.f;
#pragma unroll
    for (int w2 = 0; w2 < 8; ++w2) S += redS[w2][row] * __expf(redM[w2][row] - M);
    float invS = 1.f / S;
    size_t pb = ((size_t)bh * 1024 + q0 + row) * 1024;
#pragma unroll
    for (int it = 0; it < 8; ++it) {
      float f = __expf(redM[it][row] - M) * invS;
      int c8 = it * 16 + cb;
      bf16x8 v = *(const bf16x8*)&Pls[row * PLD + c8 * 8];
      f32x4 a, b;
#pragma unroll
      for (int j = 0; j < 4; ++j) {
        a[j] = bf2f((u16)v[j]) * f;
        b[j] = bf2f((u16)v[4 + j]) * f;
      }
      size_t off = pb + (size_t)c8 * 8;
      __builtin_nontemporal_store(a, (f32x4*)&Pout[off]);
      __builtin_nontemporal_store(b, (f32x4*)&Pout[off + 4]);
    }
  }
}

extern "C" void kernel_launch(void* const* d_in, const int* in_sizes, int n_in,
                              void* d_out, int out_size, void* d_ws, size_t ws_size,
                              hipStream_t stream) {
  const float* seq   = (const float*)d_in[0];
  const float* qkv_w = (const float*)d_in[2];
  const float* qkv_b = (const float*)d_in[3];
  const float* out_w = (const float*)d_in[4];
  const float* out_b = (const float*)d_in[5];
  float* out = (float*)d_out;

  u16* seqb = (u16*)d_ws;
  u16* Qb   = seqb + 8388608;
  u16* Kb   = Qb + 8388608;
  u16* Vtb  = Kb + 8388608;
  u16* Ob   = Vtb + 8388608;
  u16* qkvT = Ob + 8388608;
  u16* owT  = qkvT + 3145728;

  cvt_f32_bf16<<<8388608 / (256 * 8), 256, 0, stream>>>(seq, seqb, 8388608 / 8);
  transpose_cvt<<<dim3(3072 / 32, 1024 / 32), dim3(32, 8), 0, stream>>>(qkv_w, qkvT, 1024, 3072);
  transpose_cvt<<<dim3(1024 / 32, 1024 / 32), dim3(32, 8), 0, stream>>>(out_w, owT, 1024, 1024);
  qkv_gemm<<<dim3(3072 / TBN, 8192 / TBM), 256, 0, stream>>>(seqb, qkvT, qkv_b, Qb, Kb, Vtb);
  attn_kernel<<<dim3(4096), 512, 0, stream>>>(Qb, Kb, Vtb, out + 8388608, Ob);
  out_gemm<<<dim3(1024 / TBN, 8192 / TBM), 256, 0, stream>>>(Ob, owT, out_b, out);
}